// Round 1
// baseline (410.140 us; speedup 1.0000x reference)
//
#include <hip/hip_runtime.h>
#include <hip/hip_bf16.h>
#include <stdint.h>

typedef unsigned short u16;
typedef __attribute__((ext_vector_type(8))) __bf16 bf16x8;
typedef __attribute__((ext_vector_type(4))) float f32x4;

#define DEV static __device__ __forceinline__

DEV u16 f2bf(float f){
  __hip_bfloat16 h = __float2bfloat16(f);
  return *reinterpret_cast<u16*>(&h);
}
DEV float bf2f(u16 u){
  __hip_bfloat16 h;
  *reinterpret_cast<u16*>(&h) = u;
  return __bfloat162float(h);
}
DEV f32x4 mfma16(bf16x8 a, bf16x8 b, f32x4 c){
  return __builtin_amdgcn_mfma_f32_16x16x32_bf16(a, b, c, 0, 0, 0);
}
DEV bf16x8 ldfrag(const u16* p){ return *reinterpret_cast<const bf16x8*>(p); }

// ---------------------------------------------------------------- prep
__global__ void k_cvt_bf16(const float* __restrict__ src, u16* __restrict__ dst){
  size_t i = ((size_t)blockIdx.x * 256 + threadIdx.x) * 4;
  float4 v = *reinterpret_cast<const float4*>(src + i);
  ushort4 o;
  o.x = f2bf(v.x); o.y = f2bf(v.y); o.z = f2bf(v.z); o.w = f2bf(v.w);
  *reinterpret_cast<ushort4*>(dst + i) = o;
}

// src [R][C] fp32 -> dst [C][R] bf16
__global__ void k_transpose(const float* __restrict__ src, u16* __restrict__ dst,
                            int R, int C){
  __shared__ u16 t[32][33];
  int bx = blockIdx.x * 32, by = blockIdx.y * 32;
  int tx = threadIdx.x;
  for (int dy = threadIdx.y; dy < 32; dy += 8)
    t[dy][tx] = f2bf(src[(size_t)(by + dy) * C + bx + tx]);
  __syncthreads();
  for (int dy = threadIdx.y; dy < 32; dy += 8)
    dst[(size_t)(bx + dy) * R + by + tx] = t[tx][dy];
}

// ---------------------------------------------------------------- GEMM
// C[M,N] = A[M,K](bf16,row) * BT[N,K](bf16,row)^T ; 128x128 tile, 4 waves.
// EPI: 0=store bf16, 1=swish bf16, 2=gate(out0=f fp32,out1=s fp32), 3=fp32
template<int EPI>
__global__ __launch_bounds__(256) void k_gemm(
    const u16* __restrict__ A, const u16* __restrict__ BT,
    int K, int N, void* __restrict__ out0, void* __restrict__ out1)
{
  __shared__ u16 As[128 * 32];
  __shared__ u16 Bs[128 * 32];
  const int tid  = threadIdx.x;
  const int lane = tid & 63;
  const int wv   = tid >> 6;
  const int brow = blockIdx.x * 128;
  const int bcol = blockIdx.y * 128;
  const int wr   = (wv >> 1) * 64;
  const int wc   = (wv & 1) * 64;
  const int l15  = lane & 15;
  const int koff = (lane >> 4) * 8;

  f32x4 acc[4][4];
#pragma unroll
  for (int i = 0; i < 4; i++)
#pragma unroll
    for (int j = 0; j < 4; j++) acc[i][j] = f32x4{0.f, 0.f, 0.f, 0.f};

  for (int kt = 0; kt < K; kt += 32){
    __syncthreads();
#pragma unroll
    for (int q = 0; q < 2; q++){
      int cid = tid * 2 + q;            // 0..511 chunk of 8 bf16
      int row = cid >> 2, c8 = (cid & 3) * 8;
      uint4 av = *reinterpret_cast<const uint4*>(A  + (size_t)(brow + row) * K + kt + c8);
      uint4 bv = *reinterpret_cast<const uint4*>(BT + (size_t)(bcol + row) * K + kt + c8);
      *reinterpret_cast<uint4*>(&As[row * 32 + c8]) = av;
      *reinterpret_cast<uint4*>(&Bs[row * 32 + c8]) = bv;
    }
    __syncthreads();
    bf16x8 af[4], bfv[4];
#pragma unroll
    for (int i = 0; i < 4; i++) af[i]  = ldfrag(&As[(wr + i * 16 + l15) * 32 + koff]);
#pragma unroll
    for (int j = 0; j < 4; j++) bfv[j] = ldfrag(&Bs[(wc + j * 16 + l15) * 32 + koff]);
#pragma unroll
    for (int i = 0; i < 4; i++)
#pragma unroll
      for (int j = 0; j < 4; j++)
        acc[i][j] = mfma16(af[i], bfv[j], acc[i][j]);
  }

#pragma unroll
  for (int i = 0; i < 4; i++){
#pragma unroll
    for (int j = 0; j < 4; j++){
#pragma unroll
      for (int r = 0; r < 4; r++){
        int orow = brow + wr + i * 16 + (lane >> 4) * 4 + r;
        int ocol = bcol + wc + j * 16 + l15;
        size_t oi = (size_t)orow * N + ocol;
        float v = acc[i][j][r];
        if constexpr (EPI == 0){
          ((u16*)out0)[oi] = f2bf(v);
        } else if constexpr (EPI == 1){
          float sw = v / (1.f + __expf(-v));
          ((u16*)out0)[oi] = f2bf(sw);
        } else if constexpr (EPI == 2){
          float ls = (v >= 0.f) ? -log1pf(__expf(-v)) : (v - log1pf(__expf(v)));
          float f = ls * 0.125f;               // log_sigmoid / 8
          ((float*)out0)[oi] = f;              // g
          ((float*)out1)[oi] = 1.f - __expf(f);// s
        } else {
          ((float*)out0)[oi] = v;
        }
      }
    }
  }
}

// ---------------------------------------------------------------- pass A
// per (b,h,chunk): U_kT[m][kd] = sum_i Sh[i][m] K[i][kd]; U_vT[vd][m] = sum_i V[i][vd] Sh[i][m]
// Sh[i][m] = s[i][m]*exp(cum63[m]-cum[i][m]); Alast[m]=exp(cum63[m])
__global__ __launch_bounds__(256) void k_pass_a(
    const u16* __restrict__ kb, const u16* __restrict__ vb,
    const float* __restrict__ sbuf, const float* __restrict__ gbuf,
    u16* __restrict__ UkT, u16* __restrict__ UvT, float* __restrict__ Alast)
{
  __shared__ float gt[4096];
  __shared__ float st[4096];
  __shared__ float cum[4096];
  __shared__ u16 ShT[64 * 72];
  __shared__ u16 KT[256 * 72];
  __shared__ u16 VT[256 * 72];
  const int bc = blockIdx.x;
  const int bh = bc >> 5, c = bc & 31;
  const int b = bh >> 2, h = bh & 3;
  const int row0 = b * 2048 + c * 64;
  const int tid = threadIdx.x;
  const int lane = tid & 63, wv = tid >> 6;
  const int l15 = lane & 15, koff = (lane >> 4) * 8;

  for (int idx = tid; idx < 4096; idx += 256){
    int i = idx >> 6, m = idx & 63;
    gt[idx] = gbuf[(size_t)(row0 + i) * 256 + h * 64 + m];
    st[idx] = sbuf[(size_t)(row0 + i) * 256 + h * 64 + m];
  }
  __syncthreads();
  if (tid < 64){
    float cs = 0.f;
    for (int i = 0; i < 64; i++){ cs += gt[i * 64 + tid]; cum[i * 64 + tid] = cs; }
    Alast[(size_t)bc * 64 + tid] = __expf(cs);
  }
  __syncthreads();
  for (int idx = tid; idx < 4096; idx += 256){
    int i = idx >> 6, m = idx & 63;
    ShT[m * 72 + i] = f2bf(st[idx] * __expf(cum[63 * 64 + m] - cum[idx]));
  }
  for (int idx = tid * 4; idx < 16384; idx += 1024){
    int i = idx >> 8, kd = idx & 255;
    size_t g = (size_t)(row0 + i) * 1024 + h * 256 + kd;
    ushort4 kv = *reinterpret_cast<const ushort4*>(kb + g);
    ushort4 vv = *reinterpret_cast<const ushort4*>(vb + g);
    KT[(kd + 0) * 72 + i] = kv.x; KT[(kd + 1) * 72 + i] = kv.y;
    KT[(kd + 2) * 72 + i] = kv.z; KT[(kd + 3) * 72 + i] = kv.w;
    VT[(kd + 0) * 72 + i] = vv.x; VT[(kd + 1) * 72 + i] = vv.y;
    VT[(kd + 2) * 72 + i] = vv.z; VT[(kd + 3) * 72 + i] = vv.w;
  }
  __syncthreads();

  { // U_kT : rows m (wave wv -> 16 rows), cols 256
    f32x4 acc[16];
#pragma unroll
    for (int n = 0; n < 16; n++) acc[n] = f32x4{0.f, 0.f, 0.f, 0.f};
#pragma unroll
    for (int ks = 0; ks < 2; ks++){
      bf16x8 a = ldfrag(&ShT[(wv * 16 + l15) * 72 + ks * 32 + koff]);
#pragma unroll
      for (int n = 0; n < 16; n++){
        bf16x8 bb = ldfrag(&KT[(n * 16 + l15) * 72 + ks * 32 + koff]);
        acc[n] = mfma16(a, bb, acc[n]);
      }
    }
#pragma unroll
    for (int n = 0; n < 16; n++)
#pragma unroll
      for (int r = 0; r < 4; r++){
        int m = wv * 16 + (lane >> 4) * 4 + r;
        UkT[((size_t)bc * 64 + m) * 256 + n * 16 + l15] = f2bf(acc[n][r]);
      }
  }
  { // U_vT : rows vd (wave wv -> 64 rows), cols 64
    f32x4 acc[4][4];
#pragma unroll
    for (int i = 0; i < 4; i++)
#pragma unroll
      for (int j = 0; j < 4; j++) acc[i][j] = f32x4{0.f, 0.f, 0.f, 0.f};
#pragma unroll
    for (int ks = 0; ks < 2; ks++){
      bf16x8 a[4], bb[4];
#pragma unroll
      for (int mt = 0; mt < 4; mt++)
        a[mt] = ldfrag(&VT[(wv * 64 + mt * 16 + l15) * 72 + ks * 32 + koff]);
#pragma unroll
      for (int nt = 0; nt < 4; nt++)
        bb[nt] = ldfrag(&ShT[(nt * 16 + l15) * 72 + ks * 32 + koff]);
#pragma unroll
      for (int mt = 0; mt < 4; mt++)
#pragma unroll
        for (int nt = 0; nt < 4; nt++)
          acc[mt][nt] = mfma16(a[mt], bb[nt], acc[mt][nt]);
    }
#pragma unroll
    for (int mt = 0; mt < 4; mt++)
#pragma unroll
      for (int nt = 0; nt < 4; nt++)
#pragma unroll
        for (int r = 0; r < 4; r++){
          int vd = wv * 64 + mt * 16 + (lane >> 4) * 4 + r;
          UvT[((size_t)bc * 256 + vd) * 64 + nt * 16 + l15] = f2bf(acc[mt][nt][r]);
        }
  }
}

// ---------------------------------------------------------------- pass B
// sequential scan over 32 chunks; snapshots h0 written IN PLACE over U buffers
__global__ __launch_bounds__(1024) void k_pass_b(
    u16* __restrict__ UkT, u16* __restrict__ UvT, const float* __restrict__ Alast)
{
  const int bh = blockIdx.x;
  const int tid = threadIdx.x;
  __shared__ float al[64];
  float hk[16], hv[16];
#pragma unroll
  for (int j = 0; j < 16; j++){ hk[j] = 0.f; hv[j] = 0.f; }
  for (int c = 0; c < 32; c++){
    const size_t bc = (size_t)bh * 32 + c;
    __syncthreads();
    if (tid < 64) al[tid] = Alast[bc * 64 + tid];
    __syncthreads();
    const size_t base = bc * 16384;
#pragma unroll
    for (int j = 0; j < 4; j++){
      const int e = (tid + j * 1024) * 4;
      const size_t o1 = base + e;
      ushort4 uk = *reinterpret_cast<ushort4*>(&UkT[o1]);
      ushort4 uv = *reinterpret_cast<ushort4*>(&UvT[o1]);
      ushort4 sk, sv;
      sk.x = f2bf(hk[j*4+0]); sk.y = f2bf(hk[j*4+1]); sk.z = f2bf(hk[j*4+2]); sk.w = f2bf(hk[j*4+3]);
      sv.x = f2bf(hv[j*4+0]); sv.y = f2bf(hv[j*4+1]); sv.z = f2bf(hv[j*4+2]); sv.w = f2bf(hv[j*4+3]);
      *reinterpret_cast<ushort4*>(&UkT[o1]) = sk;
      *reinterpret_cast<ushort4*>(&UvT[o1]) = sv;
      const float alk = al[e >> 8];
      hk[j*4+0] = hk[j*4+0] * alk + bf2f(uk.x);
      hk[j*4+1] = hk[j*4+1] * alk + bf2f(uk.y);
      hk[j*4+2] = hk[j*4+2] * alk + bf2f(uk.z);
      hk[j*4+3] = hk[j*4+3] * alk + bf2f(uk.w);
      const int mb = e & 63;
      hv[j*4+0] = hv[j*4+0] * al[mb+0] + bf2f(uv.x);
      hv[j*4+1] = hv[j*4+1] * al[mb+1] + bf2f(uv.y);
      hv[j*4+2] = hv[j*4+2] * al[mb+2] + bf2f(uv.z);
      hv[j*4+3] = hv[j*4+3] * al[mb+3] + bf2f(uv.w);
    }
  }
}

// ---------------------------------------------------------------- pass C
__global__ __launch_bounds__(256) void k_pass_c(
    const u16* __restrict__ qb, const u16* __restrict__ kb, const u16* __restrict__ vb,
    const float* __restrict__ sbuf, const float* __restrict__ gbuf,
    const u16* __restrict__ hk0T, const u16* __restrict__ hv0T,
    const float* __restrict__ gnw, u16* __restrict__ omid)
{
  __shared__ float gt[4096];
  __shared__ float st[4096];
  __shared__ float cum[4096];
  __shared__ u16 Sh [64 * 72];
  __shared__ u16 ShT[64 * 72];
  __shared__ u16 QKm[64 * 72];
  __shared__ u16 Pt [64 * 72];
  __shared__ u16 VT [256 * 72];
  const int bc = blockIdx.x;
  const int bh = bc >> 5, c = bc & 31;
  const int b = bh >> 2, h = bh & 3;
  const int row0 = b * 2048 + c * 64;
  const int tid = threadIdx.x, lane = tid & 63, wv = tid >> 6;
  const int l15 = lane & 15, koff = (lane >> 4) * 8;
  const int irow = wv * 16;

  for (int idx = tid; idx < 4096; idx += 256){
    int i = idx >> 6, m = idx & 63;
    gt[idx] = gbuf[(size_t)(row0 + i) * 256 + h * 64 + m];
    st[idx] = sbuf[(size_t)(row0 + i) * 256 + h * 64 + m];
  }
  __syncthreads();
  if (tid < 64){
    float cs = 0.f;
    for (int i = 0; i < 64; i++){ cs += gt[i * 64 + tid]; cum[i * 64 + tid] = cs; }
  }
  __syncthreads();
  for (int idx = tid; idx < 4096; idx += 256){
    int i = idx >> 6, m = idx & 63;
    u16 v = f2bf(st[idx] * __expf(-cum[idx]));
    Sh[i * 72 + m] = v;
    ShT[m * 72 + i] = v;
  }
  for (int idx = tid * 4; idx < 16384; idx += 1024){
    int i = idx >> 8, kd = idx & 255;
    ushort4 vv = *reinterpret_cast<const ushort4*>(vb + (size_t)(row0 + i) * 1024 + h * 256 + kd);
    VT[(kd + 0) * 72 + i] = vv.x; VT[(kd + 1) * 72 + i] = vv.y;
    VT[(kd + 2) * 72 + i] = vv.z; VT[(kd + 3) * 72 + i] = vv.w;
  }
  __syncthreads();

  // phase 1: QK^T (unscaled), tril mask -> QKm
  {
    f32x4 qk[4];
#pragma unroll
    for (int n = 0; n < 4; n++) qk[n] = f32x4{0.f, 0.f, 0.f, 0.f};
#pragma unroll
    for (int ks = 0; ks < 8; ks++){
      bf16x8 a = ldfrag(qb + (size_t)(row0 + irow + l15) * 1024 + h * 256 + ks * 32 + koff);
#pragma unroll
      for (int nt = 0; nt < 4; nt++){
        bf16x8 bb = ldfrag(kb + (size_t)(row0 + nt * 16 + l15) * 1024 + h * 256 + ks * 32 + koff);
        qk[nt] = mfma16(a, bb, qk[nt]);
      }
    }
#pragma unroll
    for (int nt = 0; nt < 4; nt++)
#pragma unroll
      for (int r = 0; r < 4; r++){
        int i = irow + (lane >> 4) * 4 + r;
        int j = nt * 16 + l15;
        QKm[i * 72 + j] = f2bf((j <= i) ? qk[nt][r] : 0.f);
      }
  }
  __syncthreads();

  // phase 2: L = exp(cum)*scale*(Q hk0^T + QKm S~) ; softmax over m ; Pt = p*A
  {
    f32x4 lac[4];
#pragma unroll
    for (int n = 0; n < 4; n++) lac[n] = f32x4{0.f, 0.f, 0.f, 0.f};
#pragma unroll
    for (int ks = 0; ks < 8; ks++){
      bf16x8 a = ldfrag(qb + (size_t)(row0 + irow + l15) * 1024 + h * 256 + ks * 32 + koff);
#pragma unroll
      for (int nt = 0; nt < 4; nt++){
        bf16x8 bb = ldfrag(hk0T + ((size_t)bc * 64 + nt * 16 + l15) * 256 + ks * 32 + koff);
        lac[nt] = mfma16(a, bb, lac[nt]);
      }
    }
#pragma unroll
    for (int ks = 0; ks < 2; ks++){
      bf16x8 a = ldfrag(&QKm[(irow + l15) * 72 + ks * 32 + koff]);
#pragma unroll
      for (int nt = 0; nt < 4; nt++){
        bf16x8 bb = ldfrag(&ShT[(nt * 16 + l15) * 72 + ks * 32 + koff]);
        lac[nt] = mfma16(a, bb, lac[nt]);
      }
    }
#pragma unroll
    for (int r = 0; r < 4; r++){
      int i = irow + (lane >> 4) * 4 + r;
      float ai[4], Lv[4];
      float mx = -3.4e38f;
#pragma unroll
      for (int nt = 0; nt < 4; nt++){
        ai[nt] = __expf(cum[i * 64 + nt * 16 + l15]);
        Lv[nt] = ai[nt] * 0.0625f * lac[nt][r];
        mx = fmaxf(mx, Lv[nt]);
      }
#pragma unroll
      for (int d = 1; d < 16; d <<= 1) mx = fmaxf(mx, __shfl_xor(mx, d, 16));
      float sum = 0.f;
#pragma unroll
      for (int nt = 0; nt < 4; nt++){ Lv[nt] = __expf(Lv[nt] - mx); sum += Lv[nt]; }
#pragma unroll
      for (int d = 1; d < 16; d <<= 1) sum += __shfl_xor(sum, d, 16);
      float inv = 1.f / sum;
#pragma unroll
      for (int nt = 0; nt < 4; nt++)
        Pt[i * 72 + nt * 16 + l15] = f2bf(Lv[nt] * inv * ai[nt]);
    }
  }
  __syncthreads();

  // phase 3: W = tril(Pt S~^T) -> overwrite QKm
  {
    f32x4 wac[4];
#pragma unroll
    for (int n = 0; n < 4; n++) wac[n] = f32x4{0.f, 0.f, 0.f, 0.f};
#pragma unroll
    for (int ks = 0; ks < 2; ks++){
      bf16x8 a = ldfrag(&Pt[(irow + l15) * 72 + ks * 32 + koff]);
#pragma unroll
      for (int nt = 0; nt < 4; nt++){
        bf16x8 bb = ldfrag(&Sh[(nt * 16 + l15) * 72 + ks * 32 + koff]);
        wac[nt] = mfma16(a, bb, wac[nt]);
      }
    }
    __syncthreads();
#pragma unroll
    for (int nt = 0; nt < 4; nt++)
#pragma unroll
      for (int r = 0; r < 4; r++){
        int i = irow + (lane >> 4) * 4 + r;
        int j = nt * 16 + l15;
        QKm[i * 72 + j] = f2bf((j <= i) ? wac[nt][r] : 0.f);
      }
  }
  __syncthreads();

  // phase 4: O = Pt hv0 + W V ; fused per-head RMSNorm * g_norm_w
  {
    f32x4 oac[16];
#pragma unroll
    for (int n = 0; n < 16; n++) oac[n] = f32x4{0.f, 0.f, 0.f, 0.f};
#pragma unroll
    for (int ks = 0; ks < 2; ks++){
      bf16x8 a = ldfrag(&Pt[(irow + l15) * 72 + ks * 32 + koff]);
#pragma unroll
      for (int nt = 0; nt < 16; nt++){
        bf16x8 bb = ldfrag(hv0T + ((size_t)bc * 256 + nt * 16 + l15) * 64 + ks * 32 + koff);
        oac[nt] = mfma16(a, bb, oac[nt]);
      }
    }
#pragma unroll
    for (int ks = 0; ks < 2; ks++){
      bf16x8 a = ldfrag(&QKm[(irow + l15) * 72 + ks * 32 + koff]);
#pragma unroll
      for (int nt = 0; nt < 16; nt++){
        bf16x8 bb = ldfrag(&VT[(nt * 16 + l15) * 72 + ks * 32 + koff]);
        oac[nt] = mfma16(a, bb, oac[nt]);
      }
    }
    float gn[16];
#pragma unroll
    for (int nt = 0; nt < 16; nt++) gn[nt] = gnw[nt * 16 + l15];
#pragma unroll
    for (int r = 0; r < 4; r++){
      float ss = 0.f;
#pragma unroll
      for (int nt = 0; nt < 16; nt++) ss += oac[nt][r] * oac[nt][r];
#pragma unroll
      for (int d = 1; d < 16; d <<= 1) ss += __shfl_xor(ss, d, 16);
      float rin = rsqrtf(ss * (1.f / 256.f) + 1e-5f);
      int i = irow + (lane >> 4) * 4 + r;
#pragma unroll
      for (int nt = 0; nt < 16; nt++)
        omid[(size_t)(row0 + i) * 1024 + h * 256 + nt * 16 + l15] = f2bf(oac[nt][r] * rin * gn[nt]);
    }
  }
}

// ---------------------------------------------------------------- launch
extern "C" void kernel_launch(void* const* d_in, const int* in_sizes, int n_in,
                              void* d_out, int out_size, void* d_ws, size_t ws_size,
                              hipStream_t stream)
{
  const float* x   = (const float*)d_in[0];
  const float* Wq  = (const float*)d_in[1];
  const float* Wk  = (const float*)d_in[2];
  const float* Wv  = (const float*)d_in[3];
  const float* Wf  = (const float*)d_in[4];
  const float* gnw = (const float*)d_in[5];
  const float* Wo  = (const float*)d_in[6];
  float* out = (float*)d_out;

  char* w = (char*)d_ws;
  size_t off = 0;
  auto alloc = [&](size_t bytes)->char*{
    char* p = w + off; off += (bytes + 255) & ~(size_t)255; return p;
  };
  u16*  xb   = (u16*)alloc(8192ULL * 1024 * 2);   // later reused as o_mid
  u16*  wqT  = (u16*)alloc(1024ULL * 1024 * 2);
  u16*  wkT  = (u16*)alloc(1024ULL * 1024 * 2);
  u16*  wvT  = (u16*)alloc(1024ULL * 1024 * 2);
  u16*  woT  = (u16*)alloc(1024ULL * 1024 * 2);
  u16*  wfT  = (u16*)alloc(256ULL  * 1024 * 2);
  u16*  qb   = (u16*)alloc(8192ULL * 1024 * 2);
  u16*  kb   = (u16*)alloc(8192ULL * 1024 * 2);
  u16*  vb   = (u16*)alloc(8192ULL * 1024 * 2);
  float* sbuf  = (float*)alloc(8192ULL * 256 * 4);
  float* gbuf  = (float*)alloc(8192ULL * 256 * 4);
  u16*  UkT  = (u16*)alloc(512ULL * 64 * 256 * 2);  // becomes hk0 snapshots
  u16*  UvT  = (u16*)alloc(512ULL * 256 * 64 * 2);  // becomes hv0 snapshots
  float* alast = (float*)alloc(512ULL * 64 * 4);
  if (ws_size < off) return;  // insufficient workspace; fail cleanly

  dim3 tb(32, 8);
  k_cvt_bf16<<<8192, 256, 0, stream>>>(x, xb);
  k_transpose<<<dim3(32, 32), tb, 0, stream>>>(Wq, wqT, 1024, 1024);
  k_transpose<<<dim3(32, 32), tb, 0, stream>>>(Wk, wkT, 1024, 1024);
  k_transpose<<<dim3(32, 32), tb, 0, stream>>>(Wv, wvT, 1024, 1024);
  k_transpose<<<dim3(8, 32),  tb, 0, stream>>>(Wf, wfT, 1024, 256);
  k_transpose<<<dim3(32, 32), tb, 0, stream>>>(Wo, woT, 1024, 1024);

  k_gemm<1><<<dim3(64, 8), 256, 0, stream>>>(xb, wqT, 1024, 1024, qb, nullptr);
  k_gemm<1><<<dim3(64, 8), 256, 0, stream>>>(xb, wkT, 1024, 1024, kb, nullptr);
  k_gemm<0><<<dim3(64, 8), 256, 0, stream>>>(xb, wvT, 1024, 1024, vb, nullptr);
  k_gemm<2><<<dim3(64, 2), 256, 0, stream>>>(xb, wfT, 1024, 256, gbuf, sbuf);

  k_pass_a<<<512, 256, 0, stream>>>(kb, vb, sbuf, gbuf, UkT, UvT, alast);
  k_pass_b<<<16, 1024, 0, stream>>>(UkT, UvT, alast);
  k_pass_c<<<512, 256, 0, stream>>>(qb, kb, vb, sbuf, gbuf, UkT, UvT, gnw, xb);

  k_gemm<3><<<dim3(64, 8), 256, 0, stream>>>(xb, woT, 1024, 1024, out, nullptr);
}

// Round 2
// 316.171 us; speedup vs baseline: 1.2972x; 1.2972x over previous
//
#include <hip/hip_runtime.h>
#include <hip/hip_bf16.h>
#include <stdint.h>

typedef unsigned short u16;
typedef __attribute__((ext_vector_type(8))) __bf16 bf16x8;
typedef __attribute__((ext_vector_type(4))) float f32x4;

#define DEV static __device__ __forceinline__

DEV u16 f2bf(float f){
  __hip_bfloat16 h = __float2bfloat16(f);
  return *reinterpret_cast<u16*>(&h);
}
DEV float bf2f(u16 u){
  __hip_bfloat16 h;
  *reinterpret_cast<u16*>(&h) = u;
  return __bfloat162float(h);
}
DEV f32x4 mfma16(bf16x8 a, bf16x8 b, f32x4 c){
  return __builtin_amdgcn_mfma_f32_16x16x32_bf16(a, b, c, 0, 0, 0);
}
DEV bf16x8 ldfrag(const u16* p){ return *reinterpret_cast<const bf16x8*>(p); }

DEV void gl_lds16(const u16* g, u16* l){
  __builtin_amdgcn_global_load_lds(
      (const __attribute__((address_space(1))) void*)g,
      (__attribute__((address_space(3))) void*)l, 16, 0, 0);
}

// ---------------------------------------------------------------- prep
__global__ void k_cvt_bf16(const float* __restrict__ src, u16* __restrict__ dst){
  size_t i = ((size_t)blockIdx.x * 256 + threadIdx.x) * 4;
  float4 v = *reinterpret_cast<const float4*>(src + i);
  ushort4 o;
  o.x = f2bf(v.x); o.y = f2bf(v.y); o.z = f2bf(v.z); o.w = f2bf(v.w);
  *reinterpret_cast<ushort4*>(dst + i) = o;
}

// src [R][C] fp32 -> dst [C][R] bf16
__global__ void k_transpose(const float* __restrict__ src, u16* __restrict__ dst,
                            int R, int C){
  __shared__ u16 t[32][33];
  int bx = blockIdx.x * 32, by = blockIdx.y * 32;
  int tx = threadIdx.x;
  for (int dy = threadIdx.y; dy < 32; dy += 8)
    t[dy][tx] = f2bf(src[(size_t)(by + dy) * C + bx + tx]);
  __syncthreads();
  for (int dy = threadIdx.y; dy < 32; dy += 8)
    dst[(size_t)(bx + dy) * R + by + tx] = t[tx][dy];
}

// ---------------------------------------------------------------- GEMM
// C[M,N] = A[M,K](bf16,row) * BT[N,K](bf16,row)^T ; 128x128 tile, 4 waves.
// Staging via global_load_lds width=16 (m97 structure).
// EPI: 0=store bf16, 1=swish bf16, 2=gate(out0=f fp32,out1=s fp32), 3=fp32
template<int EPI>
__global__ __launch_bounds__(256) void k_gemm(
    const u16* __restrict__ A, const u16* __restrict__ BT,
    int K, int N, void* __restrict__ out0, void* __restrict__ out1)
{
  __shared__ u16 As[128 * 32];
  __shared__ u16 Bs[128 * 32];
  const int tid  = threadIdx.x;
  const int lane = tid & 63;
  const int wv   = tid >> 6;
  const int brow = blockIdx.x * 128;
  const int bcol = blockIdx.y * 128;
  const int wr   = (wv >> 1) * 64;
  const int wc   = (wv & 1) * 64;
  const int l15  = lane & 15;
  const int koff = (lane >> 4) * 8;
  const int lr   = lane >> 2;          // 0..15 row within 16-row block
  const int lc8  = (lane & 3) * 8;     // element offset within 32-elem row

  f32x4 acc[4][4];
#pragma unroll
  for (int i = 0; i < 4; i++)
#pragma unroll
    for (int j = 0; j < 4; j++) acc[i][j] = f32x4{0.f, 0.f, 0.f, 0.f};

  for (int kt = 0; kt < K; kt += 32){
    __syncthreads();
#pragma unroll
    for (int j = 0; j < 2; j++){
      int rb = wv * 32 + j * 16;       // block-row base this call covers
      int r  = rb + lr;
      gl_lds16(A  + (size_t)(brow + r) * K + kt + lc8, &As[rb * 32]);
      gl_lds16(BT + (size_t)(bcol + r) * K + kt + lc8, &Bs[rb * 32]);
    }
    __syncthreads();
    bf16x8 af[4], bfv[4];
#pragma unroll
    for (int i = 0; i < 4; i++) af[i]  = ldfrag(&As[(wr + i * 16 + l15) * 32 + koff]);
#pragma unroll
    for (int j = 0; j < 4; j++) bfv[j] = ldfrag(&Bs[(wc + j * 16 + l15) * 32 + koff]);
#pragma unroll
    for (int i = 0; i < 4; i++)
#pragma unroll
      for (int j = 0; j < 4; j++)
        acc[i][j] = mfma16(af[i], bfv[j], acc[i][j]);
  }

#pragma unroll
  for (int i = 0; i < 4; i++){
#pragma unroll
    for (int j = 0; j < 4; j++){
#pragma unroll
      for (int r = 0; r < 4; r++){
        int orow = brow + wr + i * 16 + (lane >> 4) * 4 + r;
        int ocol = bcol + wc + j * 16 + l15;
        size_t oi = (size_t)orow * N + ocol;
        float v = acc[i][j][r];
        if constexpr (EPI == 0){
          ((u16*)out0)[oi] = f2bf(v);
        } else if constexpr (EPI == 1){
          float sw = v / (1.f + __expf(-v));
          ((u16*)out0)[oi] = f2bf(sw);
        } else if constexpr (EPI == 2){
          float ls = (v >= 0.f) ? -log1pf(__expf(-v)) : (v - log1pf(__expf(v)));
          float f = ls * 0.125f;               // log_sigmoid / 8
          ((float*)out0)[oi] = f;              // g
          ((float*)out1)[oi] = 1.f - __expf(f);// s
        } else {
          ((float*)out0)[oi] = v;
        }
      }
    }
  }
}

// ---------------------------------------------------------------- pass A
// per (b,h,chunk): U_kT[m][kd] = sum_i Sh[i][m] K[i][kd]; U_vT[vd][m] = sum_i V[i][vd] Sh[i][m]
// Sh[i][m] = s[i][m]*exp(cum63[m]-cum[i][m]); Alast[m]=exp(cum63[m])
__global__ __launch_bounds__(256) void k_pass_a(
    const u16* __restrict__ kb, const u16* __restrict__ vb,
    const float* __restrict__ sbuf, const float* __restrict__ gbuf,
    u16* __restrict__ UkT, u16* __restrict__ UvT, float* __restrict__ Alast)
{
  __shared__ float gt[4096];
  __shared__ float st[4096];
  __shared__ float cum[4096];
  __shared__ u16 ShT[64 * 72];
  __shared__ u16 KT[256 * 72];
  __shared__ u16 VT[256 * 72];
  const int bc = blockIdx.x;
  const int bh = bc >> 5, c = bc & 31;
  const int b = bh >> 2, h = bh & 3;
  const int row0 = b * 2048 + c * 64;
  const int tid = threadIdx.x;
  const int lane = tid & 63, wv = tid >> 6;
  const int l15 = lane & 15, koff = (lane >> 4) * 8;

  for (int idx = tid; idx < 4096; idx += 256){
    int i = idx >> 6, m = idx & 63;
    gt[idx] = gbuf[(size_t)(row0 + i) * 256 + h * 64 + m];
    st[idx] = sbuf[(size_t)(row0 + i) * 256 + h * 64 + m];
  }
  __syncthreads();
  if (tid < 64){
    float cs = 0.f;
    for (int i = 0; i < 64; i++){ cs += gt[i * 64 + tid]; cum[i * 64 + tid] = cs; }
    Alast[(size_t)bc * 64 + tid] = __expf(cs);
  }
  __syncthreads();
  for (int idx = tid; idx < 4096; idx += 256){
    int i = idx >> 6, m = idx & 63;
    ShT[m * 72 + i] = f2bf(st[idx] * __expf(cum[63 * 64 + m] - cum[idx]));
  }
  for (int idx = tid * 4; idx < 16384; idx += 1024){
    int i = idx >> 8, kd = idx & 255;
    size_t g = (size_t)(row0 + i) * 1024 + h * 256 + kd;
    ushort4 kv = *reinterpret_cast<const ushort4*>(kb + g);
    ushort4 vv = *reinterpret_cast<const ushort4*>(vb + g);
    KT[(kd + 0) * 72 + i] = kv.x; KT[(kd + 1) * 72 + i] = kv.y;
    KT[(kd + 2) * 72 + i] = kv.z; KT[(kd + 3) * 72 + i] = kv.w;
    VT[(kd + 0) * 72 + i] = vv.x; VT[(kd + 1) * 72 + i] = vv.y;
    VT[(kd + 2) * 72 + i] = vv.z; VT[(kd + 3) * 72 + i] = vv.w;
  }
  __syncthreads();

  { // U_kT : rows m (wave wv -> 16 rows), cols 256
    f32x4 acc[16];
#pragma unroll
    for (int n = 0; n < 16; n++) acc[n] = f32x4{0.f, 0.f, 0.f, 0.f};
#pragma unroll
    for (int ks = 0; ks < 2; ks++){
      bf16x8 a = ldfrag(&ShT[(wv * 16 + l15) * 72 + ks * 32 + koff]);
#pragma unroll
      for (int n = 0; n < 16; n++){
        bf16x8 bb = ldfrag(&KT[(n * 16 + l15) * 72 + ks * 32 + koff]);
        acc[n] = mfma16(a, bb, acc[n]);
      }
    }
#pragma unroll
    for (int n = 0; n < 16; n++)
#pragma unroll
      for (int r = 0; r < 4; r++){
        int m = wv * 16 + (lane >> 4) * 4 + r;
        UkT[((size_t)bc * 64 + m) * 256 + n * 16 + l15] = f2bf(acc[n][r]);
      }
  }
  { // U_vT : rows vd (wave wv -> 64 rows), cols 64
    f32x4 acc[4][4];
#pragma unroll
    for (int i = 0; i < 4; i++)
#pragma unroll
      for (int j = 0; j < 4; j++) acc[i][j] = f32x4{0.f, 0.f, 0.f, 0.f};
#pragma unroll
    for (int ks = 0; ks < 2; ks++){
      bf16x8 a[4], bb[4];
#pragma unroll
      for (int mt = 0; mt < 4; mt++)
        a[mt] = ldfrag(&VT[(wv * 64 + mt * 16 + l15) * 72 + ks * 32 + koff]);
#pragma unroll
      for (int nt = 0; nt < 4; nt++)
        bb[nt] = ldfrag(&ShT[(nt * 16 + l15) * 72 + ks * 32 + koff]);
#pragma unroll
      for (int mt = 0; mt < 4; mt++)
#pragma unroll
        for (int nt = 0; nt < 4; nt++)
          acc[mt][nt] = mfma16(a[mt], bb[nt], acc[mt][nt]);
    }
#pragma unroll
    for (int mt = 0; mt < 4; mt++)
#pragma unroll
      for (int nt = 0; nt < 4; nt++)
#pragma unroll
        for (int r = 0; r < 4; r++){
          int vd = wv * 64 + mt * 16 + (lane >> 4) * 4 + r;
          UvT[((size_t)bc * 256 + vd) * 64 + nt * 16 + l15] = f2bf(acc[mt][nt][r]);
        }
  }
}

// ---------------------------------------------------------------- pass B
// Parallel across all state elements: 512 blocks (16 bh x 32 slabs),
// 256 threads, 4 scalars/thread, 2-deep prefetch over the chunk scan.
// Snapshots (state entering chunk c) overwrite U in place.
__global__ __launch_bounds__(256) void k_pass_b(
    u16* __restrict__ UkT, u16* __restrict__ UvT, const float* __restrict__ Alast)
{
  const int blk  = blockIdx.x;
  const int bh   = blk >> 5;
  const int slab = blk & 31;
  const int tid  = threadIdx.x;
  const bool isV = slab >= 16;
  u16* U = isV ? UvT : UkT;
  const int e0 = (slab & 15) * 1024 + tid * 4;
  const size_t base = (size_t)bh * 32 * 16384 + e0;
  const float* alb = Alast + (size_t)bh * 32 * 64;
  const int mK = e0 >> 8;        // multiplier index for UkT elements (same for all 4)
  const int mV = e0 & 63;        // first multiplier index for UvT elements

  float h0 = 0.f, h1 = 0.f, h2 = 0.f, h3 = 0.f;
  ushort4 u0 = *reinterpret_cast<ushort4*>(&U[base]);
  ushort4 u1 = *reinterpret_cast<ushort4*>(&U[base + 16384]);
  for (int c = 0; c < 32; c++){
    const int cn = (c + 2 < 32) ? c + 2 : 31;
    ushort4 u2 = *reinterpret_cast<ushort4*>(&U[base + (size_t)cn * 16384]);
    float a0, a1, a2, a3;
    if (isV){
      float4 av = *reinterpret_cast<const float4*>(alb + c * 64 + mV);
      a0 = av.x; a1 = av.y; a2 = av.z; a3 = av.w;
    } else {
      float av = alb[c * 64 + mK];
      a0 = a1 = a2 = a3 = av;
    }
    ushort4 s;
    s.x = f2bf(h0); s.y = f2bf(h1); s.z = f2bf(h2); s.w = f2bf(h3);
    *reinterpret_cast<ushort4*>(&U[base + (size_t)c * 16384]) = s;
    h0 = h0 * a0 + bf2f(u0.x);
    h1 = h1 * a1 + bf2f(u0.y);
    h2 = h2 * a2 + bf2f(u0.z);
    h3 = h3 * a3 + bf2f(u0.w);
    u0 = u1; u1 = u2;
  }
}

// ---------------------------------------------------------------- pass C
__global__ __launch_bounds__(256) void k_pass_c(
    const u16* __restrict__ qb, const u16* __restrict__ kb, const u16* __restrict__ vb,
    const float* __restrict__ sbuf, const float* __restrict__ gbuf,
    const u16* __restrict__ hk0T, const u16* __restrict__ hv0T,
    const float* __restrict__ gnw, u16* __restrict__ omid)
{
  __shared__ float gt[4096];
  __shared__ float st[4096];
  __shared__ float cum[4096];
  __shared__ u16 Sh [64 * 72];
  __shared__ u16 ShT[64 * 72];
  __shared__ u16 QKm[64 * 72];
  __shared__ u16 Pt [64 * 72];
  __shared__ u16 VT [256 * 72];
  const int bc = blockIdx.x;
  const int bh = bc >> 5, c = bc & 31;
  const int b = bh >> 2, h = bh & 3;
  const int row0 = b * 2048 + c * 64;
  const int tid = threadIdx.x, lane = tid & 63, wv = tid >> 6;
  const int l15 = lane & 15, koff = (lane >> 4) * 8;
  const int irow = wv * 16;

  for (int idx = tid; idx < 4096; idx += 256){
    int i = idx >> 6, m = idx & 63;
    gt[idx] = gbuf[(size_t)(row0 + i) * 256 + h * 64 + m];
    st[idx] = sbuf[(size_t)(row0 + i) * 256 + h * 64 + m];
  }
  __syncthreads();
  if (tid < 64){
    float cs = 0.f;
    for (int i = 0; i < 64; i++){ cs += gt[i * 64 + tid]; cum[i * 64 + tid] = cs; }
  }
  __syncthreads();
  for (int idx = tid; idx < 4096; idx += 256){
    int i = idx >> 6, m = idx & 63;
    u16 v = f2bf(st[idx] * __expf(-cum[idx]));
    Sh[i * 72 + m] = v;
    ShT[m * 72 + i] = v;
  }
  for (int idx = tid * 4; idx < 16384; idx += 1024){
    int i = idx >> 8, kd = idx & 255;
    ushort4 vv = *reinterpret_cast<const ushort4*>(vb + (size_t)(row0 + i) * 1024 + h * 256 + kd);
    VT[(kd + 0) * 72 + i] = vv.x; VT[(kd + 1) * 72 + i] = vv.y;
    VT[(kd + 2) * 72 + i] = vv.z; VT[(kd + 3) * 72 + i] = vv.w;
  }
  __syncthreads();

  // phase 1: QK^T (unscaled), tril mask -> QKm
  {
    f32x4 qk[4];
#pragma unroll
    for (int n = 0; n < 4; n++) qk[n] = f32x4{0.f, 0.f, 0.f, 0.f};
#pragma unroll
    for (int ks = 0; ks < 8; ks++){
      bf16x8 a = ldfrag(qb + (size_t)(row0 + irow + l15) * 1024 + h * 256 + ks * 32 + koff);
#pragma unroll
      for (int nt = 0; nt < 4; nt++){
        bf16x8 bb = ldfrag(kb + (size_t)(row0 + nt * 16 + l15) * 1024 + h * 256 + ks * 32 + koff);
        qk[nt] = mfma16(a, bb, qk[nt]);
      }
    }
#pragma unroll
    for (int nt = 0; nt < 4; nt++)
#pragma unroll
      for (int r = 0; r < 4; r++){
        int i = irow + (lane >> 4) * 4 + r;
        int j = nt * 16 + l15;
        QKm[i * 72 + j] = f2bf((j <= i) ? qk[nt][r] : 0.f);
      }
  }
  __syncthreads();

  // phase 2: L = exp(cum)*scale*(Q hk0^T + QKm S~) ; softmax over m ; Pt = p*A
  {
    f32x4 lac[4];
#pragma unroll
    for (int n = 0; n < 4; n++) lac[n] = f32x4{0.f, 0.f, 0.f, 0.f};
#pragma unroll
    for (int ks = 0; ks < 8; ks++){
      bf16x8 a = ldfrag(qb + (size_t)(row0 + irow + l15) * 1024 + h * 256 + ks * 32 + koff);
#pragma unroll
      for (int nt = 0; nt < 4; nt++){
        bf16x8 bb = ldfrag(hk0T + ((size_t)bc * 64 + nt * 16 + l15) * 256 + ks * 32 + koff);
        lac[nt] = mfma16(a, bb, lac[nt]);
      }
    }
#pragma unroll
    for (int ks = 0; ks < 2; ks++){
      bf16x8 a = ldfrag(&QKm[(irow + l15) * 72 + ks * 32 + koff]);
#pragma unroll
      for (int nt = 0; nt < 4; nt++){
        bf16x8 bb = ldfrag(&ShT[(nt * 16 + l15) * 72 + ks * 32 + koff]);
        lac[nt] = mfma16(a, bb, lac[nt]);
      }
    }
#pragma unroll
    for (int r = 0; r < 4; r++){
      int i = irow + (lane >> 4) * 4 + r;
      float ai[4], Lv[4];
      float mx = -3.4e38f;
#pragma unroll
      for (int nt = 0; nt < 4; nt++){
        ai[nt] = __expf(cum[i * 64 + nt * 16 + l15]);
        Lv[nt] = ai[nt] * 0.0625f * lac[nt][r];
        mx = fmaxf(mx, Lv[nt]);
      }
#pragma unroll
      for (int d = 1; d < 16; d <<= 1) mx = fmaxf(mx, __shfl_xor(mx, d, 16));
      float sum = 0.f;
#pragma unroll
      for (int nt = 0; nt < 4; nt++){ Lv[nt] = __expf(Lv[nt] - mx); sum += Lv[nt]; }
#pragma unroll
      for (int d = 1; d < 16; d <<= 1) sum += __shfl_xor(sum, d, 16);
      float inv = 1.f / sum;
#pragma unroll
      for (int nt = 0; nt < 4; nt++)
        Pt[i * 72 + nt * 16 + l15] = f2bf(Lv[nt] * inv * ai[nt]);
    }
  }
  __syncthreads();

  // phase 3: W = tril(Pt S~^T) -> overwrite QKm
  {
    f32x4 wac[4];
#pragma unroll
    for (int n = 0; n < 4; n++) wac[n] = f32x4{0.f, 0.f, 0.f, 0.f};
#pragma unroll
    for (int ks = 0; ks < 2; ks++){
      bf16x8 a = ldfrag(&Pt[(irow + l15) * 72 + ks * 32 + koff]);
#pragma unroll
      for (int nt = 0; nt < 4; nt++){
        bf16x8 bb = ldfrag(&Sh[(nt * 16 + l15) * 72 + ks * 32 + koff]);
        wac[nt] = mfma16(a, bb, wac[nt]);
      }
    }
    __syncthreads();
#pragma unroll
    for (int nt = 0; nt < 4; nt++)
#pragma unroll
      for (int r = 0; r < 4; r++){
        int i = irow + (lane >> 4) * 4 + r;
        int j = nt * 16 + l15;
        QKm[i * 72 + j] = f2bf((j <= i) ? wac[nt][r] : 0.f);
      }
  }
  __syncthreads();

  // phase 4: O = Pt hv0 + W V ; fused per-head RMSNorm * g_norm_w
  {
    f32x4 oac[16];
#pragma unroll
    for (int n = 0; n < 16; n++) oac[n] = f32x4{0.f, 0.f, 0.f, 0.f};
#pragma unroll
    for (int ks = 0; ks < 2; ks++){
      bf16x8 a = ldfrag(&Pt[(irow + l15) * 72 + ks * 32 + koff]);
#pragma unroll
      for (int nt = 0; nt < 16; nt++){
        bf16x8 bb = ldfrag(hv0T + ((size_t)bc * 256 + nt * 16 + l15) * 64 + ks * 32 + koff);
        oac[nt] = mfma16(a, bb, oac[nt]);
      }
    }
#pragma unroll
    for (int ks = 0; ks < 2; ks++){
      bf16x8 a = ldfrag(&QKm[(irow + l15) * 72 + ks * 32 + koff]);
#pragma unroll
      for (int nt = 0; nt < 16; nt++){
        bf16x8 bb = ldfrag(&VT[(nt * 16 + l15) * 72 + ks * 32 + koff]);
        oac[nt] = mfma16(a, bb, oac[nt]);
      }
    }
    float gn[16];
#pragma unroll
    for (int nt = 0; nt < 16; nt++) gn[nt] = gnw[nt * 16 + l15];
#pragma unroll
    for (int r = 0; r < 4; r++){
      float ss = 0.f;
#pragma unroll
      for (int nt = 0; nt < 16; nt++) ss += oac[nt][r] * oac[nt][r];
#pragma unroll
      for (int d = 1; d < 16; d <<= 1) ss += __shfl_xor(ss, d, 16);
      float rin = rsqrtf(ss * (1.f / 256.f) + 1e-5f);
      int i = irow + (lane >> 4) * 4 + r;
#pragma unroll
      for (int nt = 0; nt < 16; nt++)
        omid[(size_t)(row0 + i) * 1024 + h * 256 + nt * 16 + l15] = f2bf(oac[nt][r] * rin * gn[nt]);
    }
  }
}

// ---------------------------------------------------------------- launch
extern "C" void kernel_launch(void* const* d_in, const int* in_sizes, int n_in,
                              void* d_out, int out_size, void* d_ws, size_t ws_size,
                              hipStream_t stream)
{
  const float* x   = (const float*)d_in[0];
  const float* Wq  = (const float*)d_in[1];
  const float* Wk  = (const float*)d_in[2];
  const float* Wv  = (const float*)d_in[3];
  const float* Wf  = (const float*)d_in[4];
  const float* gnw = (const float*)d_in[5];
  const float* Wo  = (const float*)d_in[6];
  float* out = (float*)d_out;

  char* w = (char*)d_ws;
  size_t off = 0;
  auto alloc = [&](size_t bytes)->char*{
    char* p = w + off; off += (bytes + 255) & ~(size_t)255; return p;
  };
  u16*  xb   = (u16*)alloc(8192ULL * 1024 * 2);   // later reused as o_mid
  u16*  wqT  = (u16*)alloc(1024ULL * 1024 * 2);
  u16*  wkT  = (u16*)alloc(1024ULL * 1024 * 2);
  u16*  wvT  = (u16*)alloc(1024ULL * 1024 * 2);
  u16*  woT  = (u16*)alloc(1024ULL * 1024 * 2);
  u16*  wfT  = (u16*)alloc(256ULL  * 1024 * 2);
  u16*  qb   = (u16*)alloc(8192ULL * 1024 * 2);
  u16*  kb   = (u16*)alloc(8192ULL * 1024 * 2);
  u16*  vb   = (u16*)alloc(8192ULL * 1024 * 2);
  float* sbuf  = (float*)alloc(8192ULL * 256 * 4);
  float* gbuf  = (float*)alloc(8192ULL * 256 * 4);
  u16*  UkT  = (u16*)alloc(512ULL * 64 * 256 * 2);  // becomes hk0 snapshots
  u16*  UvT  = (u16*)alloc(512ULL * 256 * 64 * 2);  // becomes hv0 snapshots
  float* alast = (float*)alloc(512ULL * 64 * 4);
  if (ws_size < off) return;  // insufficient workspace; fail cleanly

  dim3 tb(32, 8);
  k_cvt_bf16<<<8192, 256, 0, stream>>>(x, xb);
  k_transpose<<<dim3(32, 32), tb, 0, stream>>>(Wq, wqT, 1024, 1024);
  k_transpose<<<dim3(32, 32), tb, 0, stream>>>(Wk, wkT, 1024, 1024);
  k_transpose<<<dim3(32, 32), tb, 0, stream>>>(Wv, wvT, 1024, 1024);
  k_transpose<<<dim3(8, 32),  tb, 0, stream>>>(Wf, wfT, 1024, 256);
  k_transpose<<<dim3(32, 32), tb, 0, stream>>>(Wo, woT, 1024, 1024);

  k_gemm<1><<<dim3(64, 8), 256, 0, stream>>>(xb, wqT, 1024, 1024, qb, nullptr);
  k_gemm<1><<<dim3(64, 8), 256, 0, stream>>>(xb, wkT, 1024, 1024, kb, nullptr);
  k_gemm<0><<<dim3(64, 8), 256, 0, stream>>>(xb, wvT, 1024, 1024, vb, nullptr);
  k_gemm<2><<<dim3(64, 2), 256, 0, stream>>>(xb, wfT, 1024, 256, gbuf, sbuf);

  k_pass_a<<<512, 256, 0, stream>>>(kb, vb, sbuf, gbuf, UkT, UvT, alast);
  k_pass_b<<<512, 256, 0, stream>>>(UkT, UvT, alast);
  k_pass_c<<<512, 256, 0, stream>>>(qb, kb, vb, sbuf, gbuf, UkT, UvT, gnw, xb);

  k_gemm<3><<<dim3(64, 8), 256, 0, stream>>>(xb, woT, 1024, 1024, out, nullptr);
}